// Round 18
// baseline (497.634 us; speedup 1.0000x reference)
//
#include <hip/hip_runtime.h>

// GCN: 3x GCNConv(tanh) + linear head. N=1e6 nodes, E=16e6 edges, fp32.
//
//   hd[i] = q16(dinv[i]*h[i]);  agg[c] = dinv[c]*((sum hd[src] + hd[c]) @ W)
//   h'[c] = tanh(agg + b)
// Round-18: r17 structure (segmented records, dispatch-separated src-half
// phases) + bpass 8-wide record processing (8 gathers in flight vs 4; phases
// are L2-latency/fill bound) + classifier fused into layer-3 phase-2 (k_final
// eliminated).

#define BKT_BITS 10
#define BKT_SZ   1024
#define MAXK     2048            // keys = bucket*2 + srchalf
#define TILE     8192            // edges per LDS sort tile (= k_hist block)
#define HTILE    4096            // TILE/2 (two int4 batches per thread)
#define CHUNK    32768           // edges per placement block (4 tiles)
#define TPC      4               // CHUNK/TILE
#define SEGC     32              // chunks per offset segment
#define MAXSEG   32
#define ATHR     1024
#define RECSENT  0xFFFFFFFFu     // impossible record (src < 2^20 => rec < 2^30)

typedef int v4i __attribute__((ext_vector_type(4)));

constexpr float XD_SCALE = 4096.0f;    // |dinv*x| <= ~5.5
constexpr float HD_SCALE = 16384.0f;   // |dinv*tanh| <= 1
constexpr int   QBIAS    = 1 << 17;    // per-edge field bias for u64 packing

__device__ __forceinline__ short q16(float v, float s) {
    int t = __float2int_rn(v * s);
    t = max(-32767, min(32767, t));
    return (short)t;
}

// load 2x int4 (8 edges) for one tile; pad with sentinel
__device__ __forceinline__ void ld_tile(const int* __restrict__ p, long t0, long t1,
                                        int tid, int4* dst, int sentinel) {
#pragma unroll
    for (int v = 0; v < 2; ++v) {
        long e = t0 + (long)v * HTILE + (long)tid * 4;
        if (e + 3 < t1) {
            dst[v] = *(const int4*)(p + e);
        } else {
            int* d = (int*)&dst[v];
#pragma unroll
            for (int j = 0; j < 4; ++j) d[j] = (e + j < t1) ? p[e + j] : sentinel;
        }
    }
}

// per-TILE key counts (key = bucket*2 + (src>=half)), u16
__global__ __launch_bounds__(ATHR) void k_hist(const int* __restrict__ row,
                                               const int* __restrict__ col, int E,
                                               unsigned short* __restrict__ cnt16,
                                               unsigned half, int NB) {
    __shared__ unsigned lh[MAXK];
    lh[threadIdx.x] = 0u; lh[threadIdx.x + 1024] = 0u;
    __syncthreads();
    long e0 = (long)blockIdx.x * TILE;
    long e1 = e0 + TILE; if (e1 > E) e1 = E;
    int4 c4[2], r4[2];
    ld_tile(col, e0, e1, threadIdx.x, c4, -1);
    ld_tile(row, e0, e1, threadIdx.x, r4, 0);
#pragma unroll
    for (int v = 0; v < 2; ++v) {
        const int* cc = (const int*)&c4[v];
        const int* rr = (const int*)&r4[v];
#pragma unroll
        for (int j = 0; j < 4; ++j) {
            unsigned b = ((unsigned)cc[j]) >> BKT_BITS;
            if (b < (unsigned)NB) {
                unsigned key = (b << 1) | (((unsigned)rr[j] >= half) ? 1u : 0u);
                atomicAdd(&lh[key], 1u);
            }
        }
    }
    __syncthreads();
    cnt16[(size_t)blockIdx.x * MAXK + threadIdx.x] = (unsigned short)lh[threadIdx.x];
    cnt16[(size_t)blockIdx.x * MAXK + threadIdx.x + 1024] =
        (unsigned short)lh[threadIdx.x + 1024];
}

// psum[seg][k] = sum of cnt16 over the segment's tiles
__global__ __launch_bounds__(256) void k_offA(const unsigned short* __restrict__ cnt16,
                                              int ntile, unsigned* __restrict__ psum) {
    int seg = blockIdx.x >> 3;
    int k = ((blockIdx.x & 7) << 8) + threadIdx.x;
    int tlo = seg * SEGC * TPC;
    int thi = (seg + 1) * SEGC * TPC; if (thi > ntile) thi = ntile;
    unsigned s = 0;
    for (int t = tlo; t < thi; ++t) s += cnt16[(size_t)t * MAXK + k];
    psum[(size_t)seg * MAXK + k] = s;
}

// kcnt[k] = sum over segments
__global__ __launch_bounds__(256) void k_totB(const unsigned* __restrict__ psum, int nseg,
                                              unsigned* __restrict__ kcnt) {
    int k = blockIdx.x * blockDim.x + threadIdx.x;
    unsigned s = 0;
    for (int g = 0; g < nseg; ++g) s += psum[(size_t)g * MAXK + k];
    kcnt[k] = s;
}

// single block: global exclusive prefix over keys
__global__ __launch_bounds__(1024) void k_scan2(const unsigned* __restrict__ kcnt,
                                                unsigned* __restrict__ kpfx) {
    __shared__ unsigned tot[MAXK], pfx[MAXK];
    int t = threadIdx.x;
    tot[t] = kcnt[t]; tot[t + 1024] = kcnt[t + 1024];
    __syncthreads();
    if (t == 0) {
        unsigned run = 0;
        for (int i = 0; i < MAXK; ++i) { pfx[i] = run; run += tot[i]; }
    }
    __syncthreads();
    kpfx[t] = pfx[t]; kpfx[t + 1024] = pfx[t + 1024];
}

// psum[seg][k] -> segment-exclusive running bases (seeded with kpfx)
__global__ __launch_bounds__(1024) void k_offB(unsigned* __restrict__ psum, int nseg,
                                               const unsigned* __restrict__ kpfx) {
    for (int k = threadIdx.x; k < MAXK; k += 1024) {
        unsigned run = kpfx[k];
        for (int g = 0; g < nseg; ++g) {
            unsigned t = psum[(size_t)g * MAXK + k];
            psum[(size_t)g * MAXK + k] = run;
            run += t;
        }
    }
}

// offs[c][k] = exclusive per-(chunk,key) placement offset (global)
__global__ __launch_bounds__(256) void k_offC(const unsigned short* __restrict__ cnt16,
                                              int ntile,
                                              const unsigned* __restrict__ psum,
                                              unsigned* __restrict__ offs, int nblk) {
    int seg = blockIdx.x >> 3;
    int k = ((blockIdx.x & 7) << 8) + threadIdx.x;
    int clo = seg * SEGC;
    int chi = clo + SEGC; if (chi > nblk) chi = nblk;
    unsigned run = psum[(size_t)seg * MAXK + k];
    for (int c = clo; c < chi; ++c) {
        offs[(size_t)c * MAXK + k] = run;
        int tlo = c * TPC, thi = tlo + TPC; if (thi > ntile) thi = ntile;
        for (int t = tlo; t < thi; ++t) run += cnt16[(size_t)t * MAXK + k];
    }
}

// ONE record-placement pass: u32 recs (src<<10|nloc) segmented by KEY.
// LDS counting sort per 8K tile (2048 keys), coalesced flush.
__global__ __launch_bounds__(ATHR, 8) void k_place(const int* __restrict__ row,
                                                   const int* __restrict__ col, int E,
                                                   const unsigned* __restrict__ offs,
                                                   const unsigned short* __restrict__ cnt16,
                                                   unsigned* __restrict__ recbuf,
                                                   unsigned half, int NB) {
    __shared__ unsigned lo[MAXK], cnt[MAXK], sc[MAXK], pc[MAXK];  // pc[0:16] scan scratch
    __shared__ unsigned rec[TILE];
    __shared__ unsigned short bkt[TILE];
    int tid = threadIdx.x, lane = tid & 63, wid = tid >> 6;
    lo[tid]        = offs[(size_t)blockIdx.x * MAXK + tid];
    lo[tid + 1024] = offs[(size_t)blockIdx.x * MAXK + tid + 1024];
    long base = (long)blockIdx.x * CHUNK;
    long bend = base + CHUNK; if (bend > E) bend = E;
    int ntl = (int)((bend - base + TILE - 1) / TILE);
    int4 fc[2], fr[2];
    {
        long t1 = min(base + TILE, bend);
        ld_tile(col, base, t1, tid, fc, -1);
        ld_tile(row, base, t1, tid, fr, 0);
    }
    for (int ti = 0; ti < ntl; ++ti) {
        // pair-key exclusive scan: thread owns keys 2t, 2t+1
        unsigned c0 = (unsigned)cnt16[(size_t)(blockIdx.x * TPC + ti) * MAXK + tid * 2];
        unsigned c1 = (unsigned)cnt16[(size_t)(blockIdx.x * TPC + ti) * MAXK + tid * 2 + 1];
        unsigned s = c0 + c1;
        unsigned v = s;
#pragma unroll
        for (int d = 1; d < 64; d <<= 1) {
            unsigned t = __shfl_up(v, d);
            if (lane >= d) v += t;
        }
        if (lane == 63) pc[wid] = v;
        __syncthreads();
        if (tid < 16) {
            unsigned w = pc[tid];
            unsigned iw = w;
#pragma unroll
            for (int d = 1; d < 16; d <<= 1) {
                unsigned t = __shfl_up(iw, d, 16);
                if (tid >= d) iw += t;
            }
            pc[tid] = iw - w;
        }
        __syncthreads();
        unsigned tbase = pc[wid] + (v - s);
        sc[tid * 2]     = tbase;
        sc[tid * 2 + 1] = tbase + c0;
        cnt[tid * 2]     = c0;
        cnt[tid * 2 + 1] = c1;
        __syncthreads();
        pc[tid] = 0u; pc[tid + 1024] = 0u;
        __syncthreads();
        int4 cc4[2] = {fc[0], fc[1]};
        int4 cr4[2] = {fr[0], fr[1]};
#pragma unroll
        for (int vv = 0; vv < 2; ++vv) {
            const int* cc = (const int*)&cc4[vv];
            const int* rr = (const int*)&cr4[vv];
#pragma unroll
            for (int j = 0; j < 4; ++j) {
                unsigned c = (unsigned)cc[j];
                unsigned b = c >> BKT_BITS;
                if (b >= (unsigned)NB) continue;   // sentinel pad
                unsigned r = (unsigned)rr[j];
                unsigned key = (b << 1) | ((r >= half) ? 1u : 0u);
                unsigned pos = sc[key] + atomicAdd(&pc[key], 1u);
                rec[pos] = (r << BKT_BITS) | (c & (BKT_SZ - 1));
                bkt[pos] = (unsigned short)key;
            }
        }
        __syncthreads();
        unsigned total = sc[MAXK - 1] + cnt[MAXK - 1];
        if (ti + 1 < ntl) {   // prefetch next tile under the flush
            long n0 = base + (long)(ti + 1) * TILE;
            long n1 = min(n0 + TILE, bend);
            ld_tile(col, n0, n1, tid, fc, -1);
            ld_tile(row, n0, n1, tid, fr, 0);
        }
        for (unsigned t = tid; t < total; t += ATHR) {
            unsigned k = bkt[t];
            recbuf[(size_t)lo[k] + (t - sc[k])] = rec[t];
        }
        __syncthreads();
        lo[tid] += cnt[tid];
        lo[tid + 1024] += cnt[tid + 1024];
        __syncthreads();
    }
}

// per-bucket in-degree (both key segments) + FUSED bufA staging (q16(dinv*x))
__global__ __launch_bounds__(ATHR) void k_bcount(const unsigned* __restrict__ recbuf,
                                                 const unsigned* __restrict__ kpfx,
                                                 const unsigned* __restrict__ kcnt,
                                                 const float* __restrict__ x,
                                                 unsigned short* __restrict__ deg,
                                                 short4* __restrict__ bufA, int N) {
    __shared__ unsigned cnt[BKT_SZ];
    int b = blockIdx.x;
    cnt[threadIdx.x] = 0u;
    __syncthreads();
#pragma unroll
    for (int h = 0; h < 2; ++h) {
        unsigned seg = ((unsigned)b << 1) | (unsigned)h;
        unsigned st = kpfx[seg], n = kcnt[seg];
        unsigned lim = st + n;
        unsigned ab = st & ~3u;
        for (unsigned j = (unsigned)threadIdx.x * 4u; j < lim - ab; j += ATHR * 4u) {
            unsigned idx = ab + j;
            if (idx >= st && idx + 4u <= lim) {
                v4i r = __builtin_nontemporal_load((const v4i*)(recbuf + idx));
                atomicAdd(&cnt[(unsigned)r.x & (BKT_SZ - 1)], 1u);
                atomicAdd(&cnt[(unsigned)r.y & (BKT_SZ - 1)], 1u);
                atomicAdd(&cnt[(unsigned)r.z & (BKT_SZ - 1)], 1u);
                atomicAdd(&cnt[(unsigned)r.w & (BKT_SZ - 1)], 1u);
            } else {
#pragma unroll
                for (int k = 0; k < 4; ++k) {
                    unsigned ii = idx + (unsigned)k;
                    if (ii >= st && ii < lim)
                        atomicAdd(&cnt[recbuf[ii] & (BKT_SZ - 1)], 1u);
                }
            }
        }
    }
    __syncthreads();
    int node = (b << BKT_BITS) + threadIdx.x;
    if (node < N) {
        unsigned short d16 = (unsigned short)cnt[threadIdx.x];
        deg[node] = d16;
        float dv = rsqrtf((float)d16 + 1.0f);  // +1 self-loop
        short4 o;
        o.x = q16(dv * x[(long)node*3 + 0], XD_SCALE);
        o.y = q16(dv * x[(long)node*3 + 1], XD_SCALE);
        o.z = q16(dv * x[(long)node*3 + 2], XD_SCALE);
        o.w = 0;
        bufA[node] = o;
    }
}

// one block per bucket, ONE half-segment per dispatch, 8-wide record loop.
// PHASE 1: segment (b<<1)   — gathers confined to src<half; acc->accg.
// PHASE 2: segment (b<<1)|1 — seed from accg, finish (optionally fused head).
template <int FIN, int FOUT, bool OUT_DINV, int PHASE, bool FINAL>
__global__ __launch_bounds__(ATHR) void k_bpass(const unsigned* __restrict__ recbuf,
                                                const unsigned* __restrict__ kpfx,
                                                const unsigned* __restrict__ kcnt,
                                                const short4* __restrict__ bufIn,
                                                float inv_s,
                                                const unsigned short* __restrict__ deg,
                                                const float* __restrict__ W,
                                                const float* __restrict__ bias,
                                                short4* __restrict__ bufOut,
                                                unsigned long long* __restrict__ accg,
                                                const float* __restrict__ Wc,
                                                const float* __restrict__ bc,
                                                float* __restrict__ out,
                                                float* __restrict__ hout,
                                                int N) {
    __shared__ unsigned long long acc[BKT_SZ][2];
    int b = blockIdx.x;
    int nodeT = (b << BKT_BITS) + threadIdx.x;   // accg padded to NB*BKT_SZ
    if (PHASE == 2) {
        acc[threadIdx.x][0] = accg[(size_t)nodeT * 2 + 0];
        acc[threadIdx.x][1] = accg[(size_t)nodeT * 2 + 1];
    } else {
        acc[threadIdx.x][0] = 0ull; acc[threadIdx.x][1] = 0ull;
    }
    __syncthreads();
    unsigned seg = ((unsigned)b << 1) | (unsigned)(PHASE - 1);
    unsigned start = kpfx[seg], n = kcnt[seg];
    unsigned lim = start + n;
    unsigned abase = start & ~3u;      // 4-aligned; 8-stride keeps v4i alignment
    unsigned tot = lim - abase;
    for (unsigned j = (unsigned)threadIdx.x * 8u; j < tot; j += ATHR * 8u) {
        unsigned idx = abase + j;
        unsigned r[8];
        if (idx >= start && idx + 8u <= lim) {
            v4i ra = __builtin_nontemporal_load((const v4i*)(recbuf + idx));
            v4i rb = __builtin_nontemporal_load((const v4i*)(recbuf + idx + 4));
            r[0] = (unsigned)ra.x; r[1] = (unsigned)ra.y;
            r[2] = (unsigned)ra.z; r[3] = (unsigned)ra.w;
            r[4] = (unsigned)rb.x; r[5] = (unsigned)rb.y;
            r[6] = (unsigned)rb.z; r[7] = (unsigned)rb.w;
        } else {
#pragma unroll
            for (int k = 0; k < 8; ++k) {
                unsigned ii = idx + (unsigned)k;
                r[k] = (ii >= start && ii < lim) ? recbuf[ii] : RECSENT;
            }
        }
        short4 q[8];
#pragma unroll
        for (int k = 0; k < 8; ++k)
            if (r[k] != RECSENT) q[k] = bufIn[r[k] >> BKT_BITS];
#pragma unroll
        for (int k = 0; k < 8; ++k) {
            if (r[k] == RECSENT) continue;
            unsigned nl = r[k] & (BKT_SZ - 1);
            unsigned long long v0 =
                ((unsigned long long)(unsigned)(q[k].y + QBIAS) << 32)
              |  (unsigned long long)(unsigned)(q[k].x + QBIAS);
            atomicAdd(&acc[nl][0], v0);
            if (FIN > 2) {
                unsigned long long v1 =
                    ((unsigned long long)(unsigned)(q[k].w + QBIAS) << 32)
                  |  (unsigned long long)(unsigned)(q[k].z + QBIAS);
                atomicAdd(&acc[nl][1], v1);
            }
        }
    }
    __syncthreads();
    if (PHASE == 1) {
        accg[(size_t)nodeT * 2 + 0] = acc[threadIdx.x][0];
        accg[(size_t)nodeT * 2 + 1] = acc[threadIdx.x][1];
        return;
    }
    int node = nodeT;
    if (node >= N) return;
    int dgi = (int)deg[node];
    long long db = (long long)dgi * QBIAS;
    float dv = rsqrtf((float)dgi + 1.0f);
    short4 qs = bufIn[node];
    unsigned long long a0_ = acc[threadIdx.x][0];
    unsigned long long a1_ = acc[threadIdx.x][1];
    float s[4] = {0.f, 0.f, 0.f, 0.f};
    s[0] = (float)((long long)(unsigned)(a0_)        - db + qs.x) * inv_s;
    s[1] = (float)((long long)(unsigned)(a0_ >> 32)  - db + qs.y) * inv_s;
    if (FIN > 2) {
        s[2] = (float)((long long)(unsigned)(a1_)       - db + qs.z) * inv_s;
        s[3] = (float)((long long)(unsigned)(a1_ >> 32) - db + qs.w) * inv_s;
    }
    float o[4] = {0.f, 0.f, 0.f, 0.f};
#pragma unroll
    for (int fo = 0; fo < FOUT; ++fo) {
        float t = 0.f;
#pragma unroll
        for (int fi = 0; fi < FIN; ++fi) t += s[fi] * W[fi * FOUT + fo];
        o[fo] = tanhf(dv * t + bias[fo]);
    }
    if (FINAL) {
        // fused classifier: out = h3@Wc + bc, hout = h3
        hout[(long)node*3 + 0] = o[0];
        hout[(long)node*3 + 1] = o[1];
        hout[(long)node*3 + 2] = o[2];
#pragma unroll
        for (int k = 0; k < 5; ++k)
            out[(long)node*5 + k] = o[0]*Wc[k] + o[1]*Wc[5+k] + o[2]*Wc[10+k] + bc[k];
        return;
    }
    float m = OUT_DINV ? dv : 1.0f;
    short4 outv;
    outv.x = q16(o[0] * m, HD_SCALE);
    outv.y = q16(o[1] * m, HD_SCALE);
    outv.z = (FOUT > 2) ? q16(o[2] * m, HD_SCALE) : (short)0;
    outv.w = (FOUT > 3) ? q16(o[3] * m, HD_SCALE) : (short)0;
    bufOut[node] = outv;
}

extern "C" void kernel_launch(void* const* d_in, const int* in_sizes, int n_in,
                              void* d_out, int out_size, void* d_ws, size_t ws_size,
                              hipStream_t stream) {
    const float* x   = (const float*)d_in[0];
    const int*   ei  = (const int*)d_in[1];   // [2,E] int32: rows then cols
    const float* W1  = (const float*)d_in[2];
    const float* b1  = (const float*)d_in[3];
    const float* W2  = (const float*)d_in[4];
    const float* b2  = (const float*)d_in[5];
    const float* W3  = (const float*)d_in[6];
    const float* b3  = (const float*)d_in[7];
    const float* Wc  = (const float*)d_in[8];
    const float* bc  = (const float*)d_in[9];

    const int N = in_sizes[0] / 3;
    const int E = in_sizes[1] / 2;
    if (N > (1 << 20)) return;                         // 20-bit src guard
    const int* row = ei;
    const int* col = ei + E;
    const int NB = (N + BKT_SZ - 1) >> BKT_BITS;
    const int ntile = (E + TILE - 1) / TILE;
    const int nblk  = (E + CHUNK - 1) / CHUNK;
    const int nseg  = (nblk + SEGC - 1) / SEGC;
    if (nseg > MAXSEG) return;
    const unsigned half = (unsigned)(N / 2);

    float* out  = (float*)d_out;                        // [N,5]
    float* hout = (float*)d_out + (long)N * 5;          // [N,3]

    // ws carve (~112 MB; ws_size ~512MB — guarded):
    char* w0 = (char*)d_ws;
    char* w = w0;
    short4* bufA = (short4*)w;                      w += (size_t)N * 8;
    short4* bufB = (short4*)w;                      w += (size_t)N * 8;
    unsigned short* deg = (unsigned short*)w;       w += (size_t)N * 2;
    unsigned short* cnt16 = (unsigned short*)w;     w += (size_t)ntile * MAXK * 2;
    unsigned* offs  = (unsigned*)w;                 w += (size_t)nblk * MAXK * 4;
    unsigned* psum  = (unsigned*)w;                 w += (size_t)MAXSEG * MAXK * 4;
    unsigned* kpfx  = (unsigned*)w;                 w += (size_t)MAXK * 4;
    unsigned* kcnt  = (unsigned*)w;                 w += (size_t)MAXK * 4;
    unsigned long long* accg = (unsigned long long*)w;
    w += (size_t)NB * BKT_SZ * 16;                  // padded to bucket grid (r14 lesson)
    unsigned* recbuf = (unsigned*)w;                w += (size_t)E * 4;
    if ((size_t)(w - w0) + 4096 > ws_size) return;     // ws guard

    // structure + degree + records (once per call)
    k_hist<<<ntile, ATHR, 0, stream>>>(row, col, E, cnt16, half, NB);
    k_offA<<<nseg * 8, 256, 0, stream>>>(cnt16, ntile, psum);
    k_totB<<<8, 256, 0, stream>>>(psum, nseg, kcnt);
    k_scan2<<<1, 1024, 0, stream>>>(kcnt, kpfx);
    k_offB<<<1, 1024, 0, stream>>>(psum, nseg, kpfx);
    k_offC<<<nseg * 8, 256, 0, stream>>>(cnt16, ntile, psum, offs, nblk);
    k_place<<<nblk, ATHR, 0, stream>>>(row, col, E, offs, cnt16, recbuf, half, NB);
    k_bcount<<<NB, ATHR, 0, stream>>>(recbuf, kpfx, kcnt, x, deg, bufA, N);

#define RUN_BPASS(FIN, FOUT, ODV, FNL, BIN, ISC, WW, BB, BOUT)                     \
    k_bpass<FIN, FOUT, ODV, 1, false><<<NB, ATHR, 0, stream>>>(recbuf, kpfx, kcnt, \
        BIN, ISC, deg, WW, BB, BOUT, accg, Wc, bc, out, hout, N);                  \
    k_bpass<FIN, FOUT, ODV, 2, FNL><<<NB, ATHR, 0, stream>>>(recbuf, kpfx, kcnt,   \
        BIN, ISC, deg, WW, BB, BOUT, accg, Wc, bc, out, hout, N);

    // layer 1: xd(bufA) -> h1d(bufB)
    RUN_BPASS(3, 4, true, false, bufA, 1.0f / XD_SCALE, W1, b1, bufB)
    // layer 2: h1d(bufB) -> h2d(bufA)
    RUN_BPASS(4, 4, true, false, bufB, 1.0f / HD_SCALE, W2, b2, bufA)
    // layer 3: h2d(bufA) -> out/hout directly (classifier fused, no k_final)
    RUN_BPASS(4, 3, false, true, bufA, 1.0f / HD_SCALE, W3, b3, bufB)
#undef RUN_BPASS
}